// Round 1
// baseline (1317.970 us; speedup 1.0000x reference)
//
#include <hip/hip_runtime.h>

#define HIDC 128
#define NGRAPH 64
#define EPSV 1e-5f
#define SLICES 16

// ---------------- CSR build ----------------

__global__ void k_count(const int* __restrict__ ei, int E, int* __restrict__ cnt) {
    int e = blockIdx.x * blockDim.x + threadIdx.x;
    if (e < E) atomicAdd(&cnt[ei[E + e]], 1);   // dst row
}

__global__ void k_scan1(const int* __restrict__ cnt, int* __restrict__ rp,
                        int* __restrict__ partial, int N) {
    const int tid = threadIdx.x;
    int base = blockIdx.x * 2048 + tid * 8;
    int v[8], pre[8];
    int tot = 0;
#pragma unroll
    for (int j = 0; j < 8; j++) {
        int idx = base + j;
        v[j] = (idx < N) ? cnt[idx] : 0;
        pre[j] = tot; tot += v[j];
    }
    __shared__ int ls[256];
    ls[tid] = tot; __syncthreads();
    for (int off = 1; off < 256; off <<= 1) {
        int add = (tid >= off) ? ls[tid - off] : 0;
        __syncthreads();
        ls[tid] += add;
        __syncthreads();
    }
    int excl = ls[tid] - tot;
#pragma unroll
    for (int j = 0; j < 8; j++) {
        int idx = base + j;
        if (idx < N) rp[idx] = excl + pre[j];
    }
    if (tid == 255) partial[blockIdx.x] = ls[255];
}

__global__ void k_scan2(const int* __restrict__ partial, int* __restrict__ offs, int NP) {
    int tid = threadIdx.x;                 // block = 64 (one wave)
    int v = (tid < NP) ? partial[tid] : 0;
    int x = v;
    for (int off = 1; off < 64; off <<= 1) {
        int y = __shfl_up(x, off);
        if (tid >= off) x += y;
    }
    if (tid < NP) offs[tid] = x - v;       // exclusive
}

__global__ void k_scan3(int* __restrict__ rp, int* __restrict__ cursor,
                        const int* __restrict__ offs, int N, int E) {
    int i = blockIdx.x * blockDim.x + threadIdx.x;
    if (i < N) {
        int v = rp[i] + offs[i >> 11];
        rp[i] = v; cursor[i] = v;
    }
    if (i == 0) rp[N] = E;
}

__global__ void k_dinv(const int* __restrict__ cnt, float* __restrict__ dinv, int N) {
    int i = blockIdx.x * blockDim.x + threadIdx.x;
    if (i < N) dinv[i] = rsqrtf((float)(cnt[i] + 1));  // +1 self loop
}

__global__ void k_fill(const int* __restrict__ ei, int E, const float* __restrict__ dinv,
                       int* __restrict__ cursor, int2* __restrict__ edata) {
    int e = blockIdx.x * blockDim.x + threadIdx.x;
    if (e >= E) return;
    int s = ei[e], d = ei[E + e];
    int p = atomicAdd(&cursor[d], 1);
    edata[p] = make_int2(s, __float_as_int(dinv[s] * dinv[d]));
}

// ---------------- transforms ----------------

__global__ void k_xform0(const float* __restrict__ x, const float* __restrict__ W0,
                         float* __restrict__ out, int N) {
    __shared__ float Wl[512];
    int tid = threadIdx.x;
    Wl[tid] = W0[tid]; Wl[tid + 256] = W0[tid + 256];
    __syncthreads();
    int gid = blockIdx.x * 256 + tid;
    int i = gid >> 7, c = gid & 127;
    if (i >= N) return;
    float4 xv = *(const float4*)&x[(size_t)i * 4];
    out[gid] = xv.x * Wl[c] + xv.y * Wl[128 + c] + xv.z * Wl[256 + c] + xv.w * Wl[384 + c];
}

__global__ void __launch_bounds__(256) k_xform(const float* __restrict__ h,
                                               const float* __restrict__ W,
                                               float* __restrict__ out, int N) {
    __shared__ float Hl[64 * 128];   // 32 KB
    int tid = threadIdx.x;
    int rbase = blockIdx.x * 64;
    for (int i = tid; i < 64 * 32; i += 256) {
        int r = (i * 4) >> 7;
        float4 v = make_float4(0.f, 0.f, 0.f, 0.f);
        if (rbase + r < N) v = *(const float4*)&h[(size_t)rbase * 128 + i * 4];
        *(float4*)&Hl[i * 4] = v;
    }
    __syncthreads();
    int c = tid & 127, rg = tid >> 7;
    float acc[32];
#pragma unroll
    for (int j = 0; j < 32; j++) acc[j] = 0.f;
    const float* Hb = &Hl[(rg * 32) * 128];
    for (int k4 = 0; k4 < 32; ++k4) {
        float w0 = W[(k4 * 4 + 0) * 128 + c];
        float w1 = W[(k4 * 4 + 1) * 128 + c];
        float w2 = W[(k4 * 4 + 2) * 128 + c];
        float w3 = W[(k4 * 4 + 3) * 128 + c];
#pragma unroll
        for (int j = 0; j < 32; j++) {
            float4 hv = *(const float4*)&Hb[j * 128 + k4 * 4];   // LDS broadcast b128
            acc[j] = fmaf(hv.x, w0, fmaf(hv.y, w1, fmaf(hv.z, w2, fmaf(hv.w, w3, acc[j]))));
        }
    }
#pragma unroll
    for (int j = 0; j < 32; j++) {
        int r = rbase + rg * 32 + j;
        if (r < N) out[(size_t)r * 128 + c] = acc[j];
    }
}

// ---------------- aggregation + bias + relu + layernorm ----------------

__global__ void __launch_bounds__(128) k_agg_ln(const float* __restrict__ tmp,
        const int2* __restrict__ edata, const int* __restrict__ rp,
        const float* __restrict__ dinv,
        const float* __restrict__ bias, const float* __restrict__ gamma,
        const float* __restrict__ beta, float* __restrict__ out, int N) {
    int node = blockIdx.x;
    int c = threadIdx.x;
    float di = dinv[node];
    float acc = di * di * tmp[(size_t)node * 128 + c];   // self loop
    int e0 = rp[node], e1 = rp[node + 1];
    for (int e = e0; e < e1; ++e) {
        int2 ed = edata[e];
        acc = fmaf(__int_as_float(ed.y), tmp[(size_t)ed.x * 128 + c], acc);
    }
    acc += bias[c];
    acc = fmaxf(acc, 0.f);
    float s1 = acc, s2 = acc * acc;
    for (int off = 32; off; off >>= 1) { s1 += __shfl_xor(s1, off); s2 += __shfl_xor(s2, off); }
    __shared__ float red[4];
    int w = c >> 6;
    if ((c & 63) == 0) { red[w] = s1; red[w + 2] = s2; }
    __syncthreads();
    s1 = red[0] + red[1]; s2 = red[2] + red[3];
    float mu  = s1 * (1.f / 128.f);
    float var = s2 * (1.f / 128.f) - mu * mu;
    float r = rsqrtf(var + EPSV);
    out[(size_t)node * 128 + c] = (acc - mu) * r * gamma[c] + beta[c];
}

// ---------------- pooling ----------------

__global__ void __launch_bounds__(128) k_pool(const float* __restrict__ h,
        const int* __restrict__ batch, float* __restrict__ featsum,
        float* __restrict__ cntg, int N) {
    int g = blockIdx.x / SLICES, s = blockIdx.x % SLICES;
    int lo = 0, hi = N;
    while (lo < hi) { int m = (lo + hi) >> 1; if (batch[m] < g) lo = m + 1; else hi = m; }
    int start = lo;
    hi = N;
    while (lo < hi) { int m = (lo + hi) >> 1; if (batch[m] < g + 1) lo = m + 1; else hi = m; }
    int end = lo;
    int len = end - start;
    if (s == 0 && threadIdx.x == 0) cntg[g] = (float)len;
    int per = (len + SLICES - 1) / SLICES;
    int a = start + s * per, b = min(a + per, end);
    float acc = 0.f;
    int c = threadIdx.x;
    for (int i = a; i < b; ++i) acc += h[(size_t)i * 128 + c];
    atomicAdd(&featsum[g * 128 + c], acc);
}

// ---------------- FC head ----------------

__global__ void __launch_bounds__(256) k_fc1(const float* __restrict__ featsum,
        const float* __restrict__ cntg, const float* __restrict__ W,
        const float* __restrict__ b, float* __restrict__ z1) {
    int g = blockIdx.x, tid = threadIdx.x;
    __shared__ float fr[128];
    if (tid < 128) fr[tid] = featsum[g * 128 + tid] / fmaxf(cntg[g], 1.f);
    __syncthreads();
    float acc[4];
#pragma unroll
    for (int j = 0; j < 4; j++) acc[j] = b[tid + 256 * j];
    for (int k = 0; k < 128; ++k) {
        float f = fr[k];
#pragma unroll
        for (int j = 0; j < 4; j++) acc[j] = fmaf(f, W[k * 1024 + tid + 256 * j], acc[j]);
    }
    float s1 = 0.f, s2 = 0.f;
#pragma unroll
    for (int j = 0; j < 4; j++) { s1 += acc[j]; s2 += acc[j] * acc[j]; }
    for (int off = 32; off; off >>= 1) { s1 += __shfl_xor(s1, off); s2 += __shfl_xor(s2, off); }
    __shared__ float red[8];
    int w = tid >> 6;
    if ((tid & 63) == 0) { red[w] = s1; red[w + 4] = s2; }
    __syncthreads();
    s1 = red[0] + red[1] + red[2] + red[3];
    s2 = red[4] + red[5] + red[6] + red[7];
    float mu = s1 * (1.f / 1024.f), var = s2 * (1.f / 1024.f) - mu * mu;
    float r = rsqrtf(var + EPSV);
#pragma unroll
    for (int j = 0; j < 4; j++)
        z1[g * 1024 + tid + 256 * j] = fmaxf((acc[j] - mu) * r, 0.f);
}

__global__ void __launch_bounds__(256) k_fc2(const float* __restrict__ z1,
        const float* __restrict__ W, const float* __restrict__ b, float* __restrict__ z2) {
    int g = blockIdx.x, tid = threadIdx.x;
    __shared__ float zr[1024];
    for (int i = tid; i < 1024; i += 256) zr[i] = z1[g * 1024 + i];
    __syncthreads();
    float acc = b[tid];
#pragma unroll 8
    for (int k = 0; k < 1024; ++k) acc = fmaf(zr[k], W[k * 256 + tid], acc);
    float s1 = acc, s2 = acc * acc;
    for (int off = 32; off; off >>= 1) { s1 += __shfl_xor(s1, off); s2 += __shfl_xor(s2, off); }
    __shared__ float red[8];
    int w = tid >> 6;
    if ((tid & 63) == 0) { red[w] = s1; red[w + 4] = s2; }
    __syncthreads();
    s1 = red[0] + red[1] + red[2] + red[3];
    s2 = red[4] + red[5] + red[6] + red[7];
    float mu = s1 * (1.f / 256.f), var = s2 * (1.f / 256.f) - mu * mu;
    float r = rsqrtf(var + EPSV);
    z2[g * 256 + tid] = fmaxf((acc - mu) * r, 0.f);
}

__global__ void k_fc3(const float* __restrict__ z2, const float* __restrict__ W,
                      const float* __restrict__ b, float* __restrict__ out) {
    int t = threadIdx.x;           // 256 threads: g = t/4, o = t%4
    int g = t >> 2, o = t & 3;
    float acc = b[o];
#pragma unroll 8
    for (int k = 0; k < 256; ++k) acc = fmaf(z2[g * 256 + k], W[k * 4 + o], acc);
    out[t] = acc;
}

// ---------------- launch ----------------

extern "C" void kernel_launch(void* const* d_in, const int* in_sizes, int n_in,
                              void* d_out, int out_size, void* d_ws, size_t ws_size,
                              hipStream_t stream) {
    const float* x    = (const float*)d_in[0];
    const int*   ei   = (const int*)d_in[1];
    const int*   batch= (const int*)d_in[2];
    const float* W0   = (const float*)d_in[3];
    const float* b0   = (const float*)d_in[4];
    const float* g0   = (const float*)d_in[5];
    const float* be0  = (const float*)d_in[6];
    const float* Wl[4]  = { W0, (const float*)d_in[7],  (const float*)d_in[11], (const float*)d_in[15] };
    const float* bl[4]  = { b0, (const float*)d_in[8],  (const float*)d_in[12], (const float*)d_in[16] };
    const float* gl[4]  = { g0, (const float*)d_in[9],  (const float*)d_in[13], (const float*)d_in[17] };
    const float* bel[4] = { be0,(const float*)d_in[10], (const float*)d_in[14], (const float*)d_in[18] };
    const float* fcW1 = (const float*)d_in[19];
    const float* fcb1 = (const float*)d_in[20];
    const float* fcW2 = (const float*)d_in[21];
    const float* fcb2 = (const float*)d_in[22];
    const float* fcW3 = (const float*)d_in[23];
    const float* fcb3 = (const float*)d_in[24];
    float* out = (float*)d_out;

    const int N = in_sizes[2];
    const int E = in_sizes[1] / 2;

    char* w = (char*)d_ws;
    auto alloc = [&](size_t bytes) -> char* {
        char* p = w; w += (bytes + 255) & ~(size_t)255; return p;
    };
    float* hA      = (float*)alloc((size_t)N * HIDC * 4);
    float* hB      = (float*)alloc((size_t)N * HIDC * 4);
    int2*  edata   = (int2*) alloc((size_t)E * 8);
    int*   rp      = (int*)  alloc((size_t)(N + 1) * 4);
    int*   cursor  = (int*)  alloc((size_t)N * 4);
    int*   cntI    = (int*)  alloc((size_t)N * 4);
    float* dinv    = (float*)alloc((size_t)N * 4);
    int*   partial = (int*)  alloc(64 * 4);
    int*   offs    = (int*)  alloc(64 * 4);
    float* featsum = (float*)alloc(NGRAPH * HIDC * 4);
    float* cntg    = (float*)alloc(NGRAPH * 4);
    float* z1      = (float*)alloc(NGRAPH * 1024 * 4);
    float* z2      = (float*)alloc(NGRAPH * 256 * 4);

    const int NCH = (N + 2047) / 2048;

    hipMemsetAsync(cntI, 0, (size_t)N * 4, stream);
    hipMemsetAsync(featsum, 0, NGRAPH * HIDC * 4, stream);

    int egrid = (E + 255) / 256;
    int ngrid = (N + 255) / 256;

    k_count<<<egrid, 256, 0, stream>>>(ei, E, cntI);
    k_scan1<<<NCH, 256, 0, stream>>>(cntI, rp, partial, N);
    k_scan2<<<1, 64, 0, stream>>>(partial, offs, NCH);
    k_scan3<<<ngrid, 256, 0, stream>>>(rp, cursor, offs, N, E);
    k_dinv<<<ngrid, 256, 0, stream>>>(cntI, dinv, N);
    k_fill<<<egrid, 256, 0, stream>>>(ei, E, dinv, cursor, edata);

    // layer 0
    k_xform0<<<(N * HIDC + 255) / 256, 256, 0, stream>>>(x, Wl[0], hB, N);
    k_agg_ln<<<N, 128, 0, stream>>>(hB, edata, rp, dinv, bl[0], gl[0], bel[0], hA, N);
    // layers 1..3
    for (int L = 1; L < 4; ++L) {
        k_xform<<<(N + 63) / 64, 256, 0, stream>>>(hA, Wl[L], hB, N);
        k_agg_ln<<<N, 128, 0, stream>>>(hB, edata, rp, dinv, bl[L], gl[L], bel[L], hA, N);
    }

    k_pool<<<NGRAPH * SLICES, 128, 0, stream>>>(hA, batch, featsum, cntg, N);
    k_fc1<<<NGRAPH, 256, 0, stream>>>(featsum, cntg, fcW1, fcb1, z1);
    k_fc2<<<NGRAPH, 256, 0, stream>>>(z1, fcW2, fcb2, z2);
    k_fc3<<<1, 256, 0, stream>>>(z2, fcW3, fcb3, out);
}

// Round 2
// 675.575 us; speedup vs baseline: 1.9509x; 1.9509x over previous
//
#include <hip/hip_runtime.h>

#define HIDC 128
#define NGRAPH 64
#define EPSV 1e-5f
#define SLICES 16

typedef __attribute__((ext_vector_type(8))) short bf16x8;
typedef __attribute__((ext_vector_type(4))) float f32x4;

__device__ inline uint bf16_rne(float f) {
    uint u = __float_as_uint(f);
    return (u + 0x7fffu + ((u >> 16) & 1u)) >> 16;
}
__device__ inline uint pack2(float a, float b) { return bf16_rne(a) | (bf16_rne(b) << 16); }
__device__ inline float blo(uint v) { return __uint_as_float(v << 16); }
__device__ inline float bhi(uint v) { return __uint_as_float(v & 0xffff0000u); }

// ---------------- CSR build ----------------

__global__ void k_count(const int* __restrict__ ei, int E, int* __restrict__ cnt) {
    int e = blockIdx.x * blockDim.x + threadIdx.x;
    if (e < E) atomicAdd(&cnt[ei[E + e]], 1);
}

__global__ void k_scan1(const int* __restrict__ cnt, int* __restrict__ rp,
                        int* __restrict__ partial, int N) {
    const int tid = threadIdx.x;
    int base = blockIdx.x * 2048 + tid * 8;
    int v[8], pre[8];
    int tot = 0;
#pragma unroll
    for (int j = 0; j < 8; j++) {
        int idx = base + j;
        v[j] = (idx < N) ? cnt[idx] : 0;
        pre[j] = tot; tot += v[j];
    }
    __shared__ int ls[256];
    ls[tid] = tot; __syncthreads();
    for (int off = 1; off < 256; off <<= 1) {
        int add = (tid >= off) ? ls[tid - off] : 0;
        __syncthreads();
        ls[tid] += add;
        __syncthreads();
    }
    int excl = ls[tid] - tot;
#pragma unroll
    for (int j = 0; j < 8; j++) {
        int idx = base + j;
        if (idx < N) rp[idx] = excl + pre[j];
    }
    if (tid == 255) partial[blockIdx.x] = ls[255];
}

__global__ void k_scan2(const int* __restrict__ partial, int* __restrict__ offs, int NP) {
    int tid = threadIdx.x;
    int v = (tid < NP) ? partial[tid] : 0;
    int x = v;
    for (int off = 1; off < 64; off <<= 1) {
        int y = __shfl_up(x, off);
        if (tid >= off) x += y;
    }
    if (tid < NP) offs[tid] = x - v;
}

__global__ void k_scan3(int* __restrict__ rp, int* __restrict__ cursor,
                        const int* __restrict__ offs, int N, int E) {
    int i = blockIdx.x * blockDim.x + threadIdx.x;
    if (i < N) {
        int v = rp[i] + offs[i >> 11];
        rp[i] = v; cursor[i] = v;
    }
    if (i == 0) rp[N] = E;
}

__global__ void k_dinv(const int* __restrict__ cnt, float* __restrict__ dinv, int N) {
    int i = blockIdx.x * blockDim.x + threadIdx.x;
    if (i < N) dinv[i] = rsqrtf((float)(cnt[i] + 1));
}

__global__ void k_fill(const int* __restrict__ ei, int E, const float* __restrict__ dinv,
                       int* __restrict__ cursor, int2* __restrict__ edata) {
    int e = blockIdx.x * blockDim.x + threadIdx.x;
    if (e >= E) return;
    int s = ei[e], d = ei[E + e];
    int p = atomicAdd(&cursor[d], 1);
    edata[p] = make_int2(s, __float_as_int(dinv[s] * dinv[d]));
}

// ---------------- layer 0: aggregate x (4ch), then transform+LN ----------------

__global__ void __launch_bounds__(256) k_agg_x(
    const float* __restrict__ x, const int2* __restrict__ edata,
    const int* __restrict__ rp, const float* __restrict__ dinv,
    float* __restrict__ ax, int N)
{
    int tid = threadIdx.x;
    int ch = tid & 3, es = (tid >> 2) & 3;
    int node = blockIdx.x * 16 + (tid >> 4);
    if (node >= N) return;
    int e0 = rp[node], e1 = rp[node + 1];
    float acc = 0.f;
    for (int e = e0 + es; e < e1; e += 4) {
        int2 ed = edata[e];
        acc = fmaf(__int_as_float(ed.y), x[(size_t)ed.x * 4 + ch], acc);
    }
    acc += __shfl_xor(acc, 4);
    acc += __shfl_xor(acc, 8);
    if (es == 0) {
        float di = dinv[node];
        acc = fmaf(di * di, x[(size_t)node * 4 + ch], acc);
        ax[(size_t)node * 4 + ch] = acc;
    }
}

__global__ void __launch_bounds__(256) k_l0_ln(
    const float* __restrict__ ax, const float* __restrict__ W0,
    const float* __restrict__ b0, const float* __restrict__ g0,
    const float* __restrict__ be0, uint* __restrict__ hA, int N)
{
    __shared__ float s[896];
    int tid = threadIdx.x;
    for (int i = tid; i < 896; i += 256) {
        float v;
        if (i < 512) v = W0[i];
        else if (i < 640) v = b0[i - 512];
        else if (i < 768) v = g0[i - 640];
        else v = be0[i - 768];
        s[i] = v;
    }
    __syncthreads();
    int lane = tid & 63;
    int node = blockIdx.x * 4 + (tid >> 6);
    if (node >= N) return;
    float4 a = *(const float4*)&ax[(size_t)node * 4];
    int c0 = 2 * lane, c1 = c0 + 1;
    float v0 = a.x * s[c0] + a.y * s[128 + c0] + a.z * s[256 + c0] + a.w * s[384 + c0] + s[512 + c0];
    float v1 = a.x * s[c1] + a.y * s[128 + c1] + a.z * s[256 + c1] + a.w * s[384 + c1] + s[512 + c1];
    v0 = fmaxf(v0, 0.f); v1 = fmaxf(v1, 0.f);
    float s1 = v0 + v1, s2 = v0 * v0 + v1 * v1;
#pragma unroll
    for (int off = 32; off; off >>= 1) { s1 += __shfl_xor(s1, off); s2 += __shfl_xor(s2, off); }
    float mu = s1 * (1.f / 128.f), var = s2 * (1.f / 128.f) - mu * mu;
    float r = rsqrtf(var + EPSV);
    float o0 = (v0 - mu) * r * s[640 + c0] + s[768 + c0];
    float o1 = (v1 - mu) * r * s[640 + c1] + s[768 + c1];
    hA[(size_t)node * 64 + lane] = pack2(o0, o1);
}

// ---------------- MFMA transform: out = h @ W (bf16 in/out, fp32 acc) ----------------

__global__ void __launch_bounds__(256) k_xform_mfma(
    const ushort* __restrict__ h,   // N x 128 bf16
    const float* __restrict__ W,    // 128 x 128 fp32 row-major [k][n]
    ushort* __restrict__ out,       // N x 128 bf16
    int N)
{
    __shared__ ushort Wt[128 * 128];   // [n][k], XOR-swizzled, 32 KB
    int tid = threadIdx.x;
    for (int idx = tid; idx < 128 * 64; idx += 256) {
        int n = idx & 127, k2 = idx >> 7;        // k2 = k-pair index
        float w0 = W[(2 * k2) * 128 + n];
        float w1 = W[(2 * k2 + 1) * 128 + n];
        int byte = (n << 8) + ((k2 << 2) ^ ((n & 7) << 4));
        *(uint*)((char*)Wt + byte) = pack2(w0, w1);
    }
    __syncthreads();

    int lane = tid & 63;
    int wv = tid >> 6;
    int m = lane & 15, g = lane >> 4;
    int rb = blockIdx.x * 128 + wv * 32;

    bf16x8 a[2][4];
#pragma unroll
    for (int mt = 0; mt < 2; mt++) {
        int r = rb + mt * 16 + m;
        const ushort* hp = h + (size_t)r * 128;
#pragma unroll
        for (int kk = 0; kk < 4; kk++) {
            bf16x8 v = {};
            if (r < N) v = *(const bf16x8*)(hp + kk * 32 + g * 8);
            a[mt][kk] = v;
        }
    }
    f32x4 acc[2][8];
#pragma unroll
    for (int mt = 0; mt < 2; mt++)
#pragma unroll
        for (int nt = 0; nt < 8; nt++) acc[mt][nt] = (f32x4){0.f, 0.f, 0.f, 0.f};

#pragma unroll
    for (int nt = 0; nt < 8; nt++) {
        int n = (lane & 15) + nt * 16;
        int rowb = n << 8;
        int swz = (n & 7) << 4;
#pragma unroll
        for (int kk = 0; kk < 4; kk++) {
            bf16x8 b = *(const bf16x8*)((const char*)Wt + (rowb + ((kk * 64 + g * 16) ^ swz)));
            acc[0][nt] = __builtin_amdgcn_mfma_f32_16x16x32_bf16(a[0][kk], b, acc[0][nt], 0, 0, 0);
            acc[1][nt] = __builtin_amdgcn_mfma_f32_16x16x32_bf16(a[1][kk], b, acc[1][nt], 0, 0, 0);
        }
    }
#pragma unroll
    for (int mt = 0; mt < 2; mt++) {
#pragma unroll
        for (int q = 0; q < 4; q++) {
            int r = rb + mt * 16 + g * 4 + q;
            if (r < N) {
#pragma unroll
                for (int nt = 0; nt < 8; nt++)
                    out[(size_t)r * 128 + (lane & 15) + nt * 16] = (ushort)bf16_rne(acc[mt][nt][q]);
            }
        }
    }
}

// ---------------- aggregation + bias + relu + LN (bf16, wave-per-node) ----------------

__global__ void __launch_bounds__(256) k_agg_ln(
    const uint* __restrict__ tmp,   // N x 64 (bf16x2)
    const int2* __restrict__ edata, const int* __restrict__ rp,
    const float* __restrict__ dinv,
    const float* __restrict__ bias, const float* __restrict__ gamma,
    const float* __restrict__ beta, uint* __restrict__ out, int N)
{
    int lane = threadIdx.x & 63;
    int node = blockIdx.x * 4 + (threadIdx.x >> 6);
    if (node >= N) return;
    float di = dinv[node];
    uint v = tmp[(size_t)node * 64 + lane];
    float ax = di * di * blo(v), ay = di * di * bhi(v);
    int e0 = rp[node], e1 = rp[node + 1];
    int e = e0;
    for (; e + 2 <= e1; e += 2) {
        int2 ea = edata[e];
        int2 eb = edata[e + 1];
        uint va = tmp[(size_t)ea.x * 64 + lane];
        uint vb = tmp[(size_t)eb.x * 64 + lane];
        float na = __int_as_float(ea.y), nb = __int_as_float(eb.y);
        ax = fmaf(na, blo(va), ax); ay = fmaf(na, bhi(va), ay);
        ax = fmaf(nb, blo(vb), ax); ay = fmaf(nb, bhi(vb), ay);
    }
    if (e < e1) {
        int2 ea = edata[e];
        uint va = tmp[(size_t)ea.x * 64 + lane];
        float na = __int_as_float(ea.y);
        ax = fmaf(na, blo(va), ax); ay = fmaf(na, bhi(va), ay);
    }
    float2 bb = *(const float2*)&bias[2 * lane];
    float a0 = fmaxf(ax + bb.x, 0.f), a1 = fmaxf(ay + bb.y, 0.f);
    float s1 = a0 + a1, s2 = a0 * a0 + a1 * a1;
#pragma unroll
    for (int off = 32; off; off >>= 1) { s1 += __shfl_xor(s1, off); s2 += __shfl_xor(s2, off); }
    float mu = s1 * (1.f / 128.f), var = s2 * (1.f / 128.f) - mu * mu;
    float r = rsqrtf(var + EPSV);
    float2 gg = *(const float2*)&gamma[2 * lane];
    float2 be = *(const float2*)&beta[2 * lane];
    float o0 = (a0 - mu) * r * gg.x + be.x;
    float o1 = (a1 - mu) * r * gg.y + be.y;
    out[(size_t)node * 64 + lane] = pack2(o0, o1);
}

// ---------------- pooling (bf16 input) ----------------

__global__ void __launch_bounds__(64) k_pool(
    const uint* __restrict__ h, const int* __restrict__ batch,
    float* __restrict__ featsum, float* __restrict__ cntg, int N)
{
    int g = blockIdx.x / SLICES, s = blockIdx.x % SLICES;
    int lane = threadIdx.x;
    int lo = 0, hi = N;
    while (lo < hi) { int m = (lo + hi) >> 1; if (batch[m] < g) lo = m + 1; else hi = m; }
    int start = lo;
    hi = N;
    while (lo < hi) { int m = (lo + hi) >> 1; if (batch[m] < g + 1) lo = m + 1; else hi = m; }
    int end = lo;
    int len = end - start;
    if (s == 0 && lane == 0) cntg[g] = (float)len;
    int per = (len + SLICES - 1) / SLICES;
    int a = start + s * per, b = min(a + per, end);
    float accx = 0.f, accy = 0.f;
    for (int i = a; i < b; ++i) {
        uint v = h[(size_t)i * 64 + lane];
        accx += blo(v); accy += bhi(v);
    }
    atomicAdd(&featsum[g * 128 + 2 * lane], accx);
    atomicAdd(&featsum[g * 128 + 2 * lane + 1], accy);
}

// ---------------- FC head (fp32, unchanged) ----------------

__global__ void __launch_bounds__(256) k_fc1(const float* __restrict__ featsum,
        const float* __restrict__ cntg, const float* __restrict__ W,
        const float* __restrict__ b, float* __restrict__ z1) {
    int g = blockIdx.x, tid = threadIdx.x;
    __shared__ float fr[128];
    if (tid < 128) fr[tid] = featsum[g * 128 + tid] / fmaxf(cntg[g], 1.f);
    __syncthreads();
    float acc[4];
#pragma unroll
    for (int j = 0; j < 4; j++) acc[j] = b[tid + 256 * j];
    for (int k = 0; k < 128; ++k) {
        float f = fr[k];
#pragma unroll
        for (int j = 0; j < 4; j++) acc[j] = fmaf(f, W[k * 1024 + tid + 256 * j], acc[j]);
    }
    float s1 = 0.f, s2 = 0.f;
#pragma unroll
    for (int j = 0; j < 4; j++) { s1 += acc[j]; s2 += acc[j] * acc[j]; }
    for (int off = 32; off; off >>= 1) { s1 += __shfl_xor(s1, off); s2 += __shfl_xor(s2, off); }
    __shared__ float red[8];
    int w = tid >> 6;
    if ((tid & 63) == 0) { red[w] = s1; red[w + 4] = s2; }
    __syncthreads();
    s1 = red[0] + red[1] + red[2] + red[3];
    s2 = red[4] + red[5] + red[6] + red[7];
    float mu = s1 * (1.f / 1024.f), var = s2 * (1.f / 1024.f) - mu * mu;
    float r = rsqrtf(var + EPSV);
#pragma unroll
    for (int j = 0; j < 4; j++)
        z1[g * 1024 + tid + 256 * j] = fmaxf((acc[j] - mu) * r, 0.f);
}

__global__ void __launch_bounds__(256) k_fc2(const float* __restrict__ z1,
        const float* __restrict__ W, const float* __restrict__ b, float* __restrict__ z2) {
    int g = blockIdx.x, tid = threadIdx.x;
    __shared__ float zr[1024];
    for (int i = tid; i < 1024; i += 256) zr[i] = z1[g * 1024 + i];
    __syncthreads();
    float acc = b[tid];
#pragma unroll 8
    for (int k = 0; k < 1024; ++k) acc = fmaf(zr[k], W[k * 256 + tid], acc);
    float s1 = acc, s2 = acc * acc;
    for (int off = 32; off; off >>= 1) { s1 += __shfl_xor(s1, off); s2 += __shfl_xor(s2, off); }
    __shared__ float red[8];
    int w = tid >> 6;
    if ((tid & 63) == 0) { red[w] = s1; red[w + 4] = s2; }
    __syncthreads();
    s1 = red[0] + red[1] + red[2] + red[3];
    s2 = red[4] + red[5] + red[6] + red[7];
    float mu = s1 * (1.f / 256.f), var = s2 * (1.f / 256.f) - mu * mu;
    float r = rsqrtf(var + EPSV);
    z2[g * 256 + tid] = fmaxf((acc - mu) * r, 0.f);
}

__global__ void k_fc3(const float* __restrict__ z2, const float* __restrict__ W,
                      const float* __restrict__ b, float* __restrict__ out) {
    int t = threadIdx.x;
    int g = t >> 2, o = t & 3;
    float acc = b[o];
#pragma unroll 8
    for (int k = 0; k < 256; ++k) acc = fmaf(z2[g * 256 + k], W[k * 4 + o], acc);
    out[t] = acc;
}

// ---------------- launch ----------------

extern "C" void kernel_launch(void* const* d_in, const int* in_sizes, int n_in,
                              void* d_out, int out_size, void* d_ws, size_t ws_size,
                              hipStream_t stream) {
    const float* x    = (const float*)d_in[0];
    const int*   ei   = (const int*)d_in[1];
    const int*   batch= (const int*)d_in[2];
    const float* Wl[4]  = { (const float*)d_in[3], (const float*)d_in[7],  (const float*)d_in[11], (const float*)d_in[15] };
    const float* bl[4]  = { (const float*)d_in[4], (const float*)d_in[8],  (const float*)d_in[12], (const float*)d_in[16] };
    const float* gl[4]  = { (const float*)d_in[5], (const float*)d_in[9],  (const float*)d_in[13], (const float*)d_in[17] };
    const float* bel[4] = { (const float*)d_in[6], (const float*)d_in[10], (const float*)d_in[14], (const float*)d_in[18] };
    const float* fcW1 = (const float*)d_in[19];
    const float* fcb1 = (const float*)d_in[20];
    const float* fcW2 = (const float*)d_in[21];
    const float* fcb2 = (const float*)d_in[22];
    const float* fcW3 = (const float*)d_in[23];
    const float* fcb3 = (const float*)d_in[24];
    float* out = (float*)d_out;

    const int N = in_sizes[2];
    const int E = in_sizes[1] / 2;

    char* w = (char*)d_ws;
    auto alloc = [&](size_t bytes) -> char* {
        char* p = w; w += (bytes + 255) & ~(size_t)255; return p;
    };
    uint*  hA      = (uint*) alloc((size_t)N * 64 * 4);   // bf16 N x 128
    uint*  hB      = (uint*) alloc((size_t)N * 64 * 4);
    float* ax      = (float*)alloc((size_t)N * 4 * 4);
    int2*  edata   = (int2*) alloc((size_t)E * 8);
    int*   rp      = (int*)  alloc((size_t)(N + 1) * 4);
    int*   cursor  = (int*)  alloc((size_t)N * 4);
    int*   cntI    = (int*)  alloc((size_t)N * 4);
    float* dinv    = (float*)alloc((size_t)N * 4);
    int*   partial = (int*)  alloc(64 * 4);
    int*   offs    = (int*)  alloc(64 * 4);
    float* featsum = (float*)alloc(NGRAPH * HIDC * 4);
    float* cntg    = (float*)alloc(NGRAPH * 4);
    float* z1      = (float*)alloc(NGRAPH * 1024 * 4);
    float* z2      = (float*)alloc(NGRAPH * 256 * 4);

    const int NCH = (N + 2047) / 2048;

    hipMemsetAsync(cntI, 0, (size_t)N * 4, stream);
    hipMemsetAsync(featsum, 0, NGRAPH * HIDC * 4, stream);

    int egrid = (E + 255) / 256;
    int ngrid = (N + 255) / 256;

    k_count<<<egrid, 256, 0, stream>>>(ei, E, cntI);
    k_scan1<<<NCH, 256, 0, stream>>>(cntI, rp, partial, N);
    k_scan2<<<1, 64, 0, stream>>>(partial, offs, NCH);
    k_scan3<<<ngrid, 256, 0, stream>>>(rp, cursor, offs, N, E);
    k_dinv<<<ngrid, 256, 0, stream>>>(cntI, dinv, N);
    k_fill<<<egrid, 256, 0, stream>>>(ei, E, dinv, cursor, edata);

    // layer 0: agg(x) then transform+bias+relu+LN
    k_agg_x<<<(N + 15) / 16, 256, 0, stream>>>(x, edata, rp, dinv, ax, N);
    k_l0_ln<<<(N + 3) / 4, 256, 0, stream>>>(ax, Wl[0], bl[0], gl[0], bel[0], hA, N);

    // layers 1..3: MFMA transform then aggregate+bias+relu+LN
    for (int L = 1; L < 4; ++L) {
        k_xform_mfma<<<(N + 127) / 128, 256, 0, stream>>>(
            (const ushort*)hA, Wl[L], (ushort*)hB, N);
        k_agg_ln<<<(N + 3) / 4, 256, 0, stream>>>(
            hB, edata, rp, dinv, bl[L], gl[L], bel[L], hA, N);
    }

    k_pool<<<NGRAPH * SLICES, 64, 0, stream>>>(hA, batch, featsum, cntg, N);
    k_fc1<<<NGRAPH, 256, 0, stream>>>(featsum, cntg, fcW1, fcb1, z1);
    k_fc2<<<NGRAPH, 256, 0, stream>>>(z1, fcW2, fcb2, z2);
    k_fc3<<<1, 256, 0, stream>>>(z2, fcW3, fcb3, out);
}